// Round 4
// baseline (2051.824 us; speedup 1.0000x reference)
//
#include <hip/hip_runtime.h>
#include <hip/hip_bf16.h>

#define HIDDEN   512
#define TSTEPS   256
#define HORIZON  24
#define BTOT     1024
#define BBLK     16
#define NWG      (BTOT / BBLK)      // 64 workgroups
#define NTHR     512                // 8 waves
#define KK       16                 // K slices (512 / 32)

typedef __attribute__((ext_vector_type(8))) __bf16         bf16x8;
typedef __attribute__((ext_vector_type(4))) float          f32x4;
typedef __attribute__((ext_vector_type(8))) unsigned short ushort8;
typedef __attribute__((ext_vector_type(4))) unsigned short us4;
typedef __attribute__((ext_vector_type(4))) unsigned int   uint4v;

__device__ __forceinline__ unsigned short f2bf(float f) {
    unsigned int u = __float_as_uint(f);
    u += 0x7FFFu + ((u >> 16) & 1u);   // RNE
    return (unsigned short)(u >> 16);
}
__device__ __forceinline__ float bf2f(unsigned short s) {
    return __uint_as_float(((unsigned int)s) << 16);
}

// LDS-ordering-only barrier: does NOT drain vmcnt, so global prefetch loads
// stay in flight across steps (unlike __syncthreads' vmcnt(0) drain).
__device__ __forceinline__ void lds_barrier() {
    asm volatile("s_waitcnt lgkmcnt(0)" ::: "memory");
    __builtin_amdgcn_s_barrier();
    asm volatile("" ::: "memory");
}

// Pack Wh (f32 [512][512], row j = out-col, inner k) into bf16 A-fragment
// order, m-tile-major: Wpk[(ntg*16 + kk)*64 + lane] holds 8 bf16 of
//   A[m = ntg*16 + (lane&15)][k = kk*32 + ((lane>>4)&3)*8 + j]
__global__ void pack_wh(const float* __restrict__ Wh, ushort8* __restrict__ Wpk) {
    int tid  = blockIdx.x * blockDim.x + threadIdx.x;   // 0..32767
    int lane = tid & 63;
    int kk   = (tid >> 6) & 15;
    int ntg  = tid >> 10;                                // global m-tile 0..31
    int col  = ntg * 16 + (lane & 15);                   // out-col
    int k0   = kk * 32 + ((lane >> 4) & 3) * 8;
    const float* src = Wh + col * HIDDEN + k0;
    ushort8 v;
#pragma unroll
    for (int j = 0; j < 8; ++j) v[j] = f2bf(src[j]);
    Wpk[(ntg * 16 + kk) * 64 + lane] = v;
}

__global__ __launch_bounds__(NTHR, 2) void rnn_main(
    const float* __restrict__ x,      // [1024][256]
    const float* __restrict__ Wx_w,   // [512]
    const float* __restrict__ Wx_b,   // [512]
    const float* __restrict__ Wh_b,   // [512]
    const float* __restrict__ fc_w,   // [24][512]
    const float* __restrict__ fc_b,   // [24]
    const bf16x8* __restrict__ Wpk,   // packed bf16 A-fragments (512 KB)
    float* __restrict__ out)          // [1024][24]
{
    // h in B-fragment-major layout: hfrag[buf][(kk*64 + lane)*8 ushorts]
    __shared__ __align__(16) unsigned short hfrag[2][KK * 64 * 8];  // 2 x 16 KB
    __shared__ float xs[TSTEPS][BBLK];                               // 16 KB

    const int tid  = threadIdx.x;
    const int lane = tid & 63;
    const int wave = tid >> 6;
    const int bb   = blockIdx.x * BBLK;
    const int arow = lane & 15;      // A/B n-index; C/D col = batch row
    const int rowg = lane >> 4;

    // stage x transposed: xs[t][r]
    for (int i = tid; i < BBLK * TSTEPS; i += NTHR) {
        int t = i & 255, r = i >> 8;
        xs[t][r] = x[(bb + r) * TSTEPS + t];
    }
    // h0 = 0
    {
        uint4v z = {0u, 0u, 0u, 0u};
        uint4v* p = (uint4v*)hfrag[0];
        p[tid] = z; p[tid + NTHR] = z;
    }

    // ---- static weights: m-tiles 0,1 pinned in registers (128 VGPRs) ----
    const bf16x8* wp0 = Wpk + ((wave * 4 + 0) * 16) * 64 + lane;
    const bf16x8* wp1 = Wpk + ((wave * 4 + 1) * 16) * 64 + lane;
    bf16x8 W0[KK], W1[KK];
#pragma unroll
    for (int kk = 0; kk < KK; ++kk) { W0[kk] = wp0[kk * 64]; W1[kk] = wp1[kk * 64]; }
    // asm-define the values so the compiler cannot rematerialize (re-load) them
#pragma unroll
    for (int kk = 0; kk < KK; ++kk) {
        asm volatile("" : "+v"(*(uint4v*)&W0[kk]), "+v"(*(uint4v*)&W1[kk]));
    }

    // ---- streamed weights: m-tiles 2,3 via 8-deep circular reg buffers ----
    const bf16x8* wp2 = Wpk + ((wave * 4 + 2) * 16) * 64 + lane;
    const bf16x8* wp3 = Wpk + ((wave * 4 + 3) * 16) * 64 + lane;
    bf16x8 sb2[8], sb3[8];
#pragma unroll
    for (int i = 0; i < 8; ++i) { sb2[i] = wp2[i * 64]; sb3[i] = wp3[i * 64]; }

    // per-lane step-invariant init constants: out-col = wave*64+mt*16+rowg*4+r
    f32x4 wxw_c[4], bias_c[4];
#pragma unroll
    for (int mt = 0; mt < 4; ++mt) {
#pragma unroll
        for (int r = 0; r < 4; ++r) {
            int oc = wave * 64 + mt * 16 + rowg * 4 + r;
            wxw_c[mt][r]  = Wx_w[oc];
            bias_c[mt][r] = Wx_b[oc] + Wh_b[oc];
        }
    }

    __syncthreads();

    for (int t = 0; t < TSTEPS; ++t) {
        const unsigned short* hr = hfrag[t & 1];
        unsigned short*       hw = hfrag[(t + 1) & 1];

        const float xv = xs[t][arow];   // batch row = arow (broadcast)

        f32x4 acc[4];
#pragma unroll
        for (int mt = 0; mt < 4; ++mt)
#pragma unroll
            for (int r = 0; r < 4; ++r) acc[mt][r] = xv * wxw_c[mt][r] + bias_c[mt][r];

#pragma unroll
        for (int kk = 0; kk < KK; ++kk) {
            bf16x8 bf = *(const bf16x8*)(hr + (kk * 64 + lane) * 8);
            acc[0] = __builtin_amdgcn_mfma_f32_16x16x32_bf16(W0[kk], bf, acc[0], 0, 0, 0);
            acc[1] = __builtin_amdgcn_mfma_f32_16x16x32_bf16(W1[kk], bf, acc[1], 0, 0, 0);
            acc[2] = __builtin_amdgcn_mfma_f32_16x16x32_bf16(sb2[kk & 7], bf, acc[2], 0, 0, 0);
            acc[3] = __builtin_amdgcn_mfma_f32_16x16x32_bf16(sb3[kk & 7], bf, acc[3], 0, 0, 0);
            // refill slot (kk&7) with slice (kk+8)&15 — step-invariant stream,
            // wraps seamlessly into the next step (prefetch distance 8 iters)
            sb2[kk & 7] = wp2[((kk + 8) & 15) * 64];
            sb3[kk & 7] = wp3[((kk + 8) & 15) * 64];
        }

        // epilogue: tanh, pack 4 consecutive out-cols -> one b64 frag-major write
#pragma unroll
        for (int mt = 0; mt < 4; ++mt) {
            us4 pk;
#pragma unroll
            for (int r = 0; r < 4; ++r) {
                float v  = acc[mt][r];
                float e  = __expf(2.0f * v);
                pk[r] = f2bf(1.0f - 2.0f / (e + 1.0f));
            }
            // out-col base = wave*64 + mt*16 + rowg*4 ; batch row = arow
            int kkp   = wave * 2 + (mt >> 1);
            int chunk = (mt * 2 + (rowg >> 1)) & 3;
            int j0    = (rowg & 1) * 4;
            *(us4*)(hw + (kkp * 64 + chunk * 16 + arow) * 8 + j0) = pk;
        }
        lds_barrier();   // LDS ordering only — weight prefetch stays in flight
    }

    // final h is in hfrag[0] (TSTEPS even). fc head: 16 x 24 outputs.
    if (tid < BBLK * HORIZON) {
        int row = tid / HORIZON;
        int ho  = tid - row * HORIZON;
        float acc = fc_b[ho];
        const float* fw = fc_w + ho * HIDDEN;
        const unsigned short* hf = hfrag[0];
#pragma unroll 4
        for (int kk = 0; kk < KK; ++kk) {
#pragma unroll
            for (int c = 0; c < 4; ++c) {
                ushort8 hv = *(const ushort8*)(hf + (kk * 64 + c * 16 + row) * 8);
#pragma unroll
                for (int j = 0; j < 8; ++j)
                    acc += bf2f(hv[j]) * fw[kk * 32 + c * 8 + j];
            }
        }
        out[(bb + row) * HORIZON + ho] = acc;
    }
}

extern "C" void kernel_launch(void* const* d_in, const int* in_sizes, int n_in,
                              void* d_out, int out_size, void* d_ws, size_t ws_size,
                              hipStream_t stream) {
    const float* x    = (const float*)d_in[0];
    const float* Wx_w = (const float*)d_in[1];
    const float* Wx_b = (const float*)d_in[2];
    const float* Wh_w = (const float*)d_in[3];
    const float* Wh_b = (const float*)d_in[4];
    const float* fc_w = (const float*)d_in[5];
    const float* fc_b = (const float*)d_in[6];
    float* out = (float*)d_out;

    ushort8* Wpk = (ushort8*)d_ws;   // 512 KB packed weights

    hipLaunchKernelGGL(pack_wh, dim3(128), dim3(256), 0, stream, Wh_w, Wpk);
    hipLaunchKernelGGL(rnn_main, dim3(NWG), dim3(NTHR), 0, stream,
                       x, Wx_w, Wx_b, Wh_b, fc_w, fc_b,
                       (const bf16x8*)Wpk, out);
}

// Round 5
// 1366.627 us; speedup vs baseline: 1.5014x; 1.5014x over previous
//
#include <hip/hip_runtime.h>
#include <hip/hip_bf16.h>

#define HIDDEN   512
#define TSTEPS   256
#define HORIZON  24
#define BTOT     1024
#define BBLK     16
#define NWG      (BTOT / BBLK)      // 64 workgroups
#define NTHR     1024               // 16 waves
#define KK       16                 // K slices (512 / 32)
#define DEPTH    8                  // circular prefetch depth per m-tile

typedef __attribute__((ext_vector_type(8))) __bf16         bf16x8;
typedef __attribute__((ext_vector_type(4))) float          f32x4;
typedef __attribute__((ext_vector_type(8))) unsigned short ushort8;
typedef __attribute__((ext_vector_type(4))) unsigned short us4;
typedef __attribute__((ext_vector_type(4))) unsigned int   uint4v;

__device__ __forceinline__ unsigned short f2bf(float f) {
    unsigned int u = __float_as_uint(f);
    u += 0x7FFFu + ((u >> 16) & 1u);   // RNE
    return (unsigned short)(u >> 16);
}
__device__ __forceinline__ float bf2f(unsigned short s) {
    return __uint_as_float(((unsigned int)s) << 16);
}

// LDS-ordering-only barrier: does NOT drain vmcnt, so global prefetch loads
// stay in flight across steps. The "memory" clobber also stops LICM from
// hoisting the (loop-invariant) weight loads out of the t-loop.
__device__ __forceinline__ void lds_barrier() {
    asm volatile("s_waitcnt lgkmcnt(0)" ::: "memory");
    __builtin_amdgcn_s_barrier();
    asm volatile("" ::: "memory");
}

// Pack Wh (f32 [512][512], row j = out-col, inner k) into bf16 A-fragment
// order, m-tile-major: Wpk[(ntg*16 + kk)*64 + lane] holds 8 bf16 of
//   A[m = ntg*16 + (lane&15)][k = kk*32 + ((lane>>4)&3)*8 + j]
__global__ void pack_wh(const float* __restrict__ Wh, ushort8* __restrict__ Wpk) {
    int tid  = blockIdx.x * blockDim.x + threadIdx.x;   // 0..32767
    int lane = tid & 63;
    int kk   = (tid >> 6) & 15;
    int ntg  = tid >> 10;                                // global m-tile 0..31
    int col  = ntg * 16 + (lane & 15);                   // out-col
    int k0   = kk * 32 + ((lane >> 4) & 3) * 8;
    const float* src = Wh + col * HIDDEN + k0;
    ushort8 v;
#pragma unroll
    for (int j = 0; j < 8; ++j) v[j] = f2bf(src[j]);
    Wpk[(ntg * 16 + kk) * 64 + lane] = v;
}

__global__ __launch_bounds__(NTHR, 4) void rnn_main(
    const float* __restrict__ x,      // [1024][256]
    const float* __restrict__ Wx_w,   // [512]
    const float* __restrict__ Wx_b,   // [512]
    const float* __restrict__ Wh_b,   // [512]
    const float* __restrict__ fc_w,   // [24][512]
    const float* __restrict__ fc_b,   // [24]
    const bf16x8* __restrict__ Wpk,   // packed bf16 A-fragments (512 KB)
    float* __restrict__ out)          // [1024][24]
{
    // h in B-fragment-major layout: hfrag[buf][(kk*64 + lane)*8 ushorts]
    // lane l's B-frag for slice kk = h[row=l&15][k = kk*32 + (l>>4)*8 .. +7]
    __shared__ __align__(16) unsigned short hfrag[2][KK * 64 * 8];  // 2 x 16 KB
    __shared__ float xs[TSTEPS][BBLK];                               // 16 KB

    const int tid  = threadIdx.x;
    const int lane = tid & 63;
    const int wave = tid >> 6;       // 0..15, owns m-tiles 2w, 2w+1
    const int bb   = blockIdx.x * BBLK;
    const int arow = lane & 15;      // A m-index / C-D col = batch row
    const int rowg = lane >> 4;

    // stage x transposed: xs[t][r]
    for (int i = tid; i < BBLK * TSTEPS; i += NTHR) {
        int t = i & 255, r = i >> 8;
        xs[t][r] = x[(bb + r) * TSTEPS + t];
    }
    // h0 = 0 (only buffer 0 needs it)
    {
        uint4v z = {0u, 0u, 0u, 0u};
        ((uint4v*)hfrag[0])[tid] = z;
    }

    // ---- streamed weights: 2 m-tiles/wave, DEPTH-deep circular buffers ----
    const bf16x8* wpA = Wpk + ((wave * 2 + 0) * 16) * 64 + lane;
    const bf16x8* wpB = Wpk + ((wave * 2 + 1) * 16) * 64 + lane;
    bf16x8 sa[DEPTH], sb[DEPTH];
#pragma unroll
    for (int i = 0; i < DEPTH; ++i) { sa[i] = wpA[i * 64]; sb[i] = wpB[i * 64]; }

    // per-lane step-invariant init constants: out-col = wave*32+mtl*16+rowg*4+r
    f32x4 wxw_c[2], bias_c[2];
#pragma unroll
    for (int mtl = 0; mtl < 2; ++mtl) {
#pragma unroll
        for (int r = 0; r < 4; ++r) {
            int oc = wave * 32 + mtl * 16 + rowg * 4 + r;
            wxw_c[mtl][r]  = Wx_w[oc];
            bias_c[mtl][r] = Wx_b[oc] + Wh_b[oc];
        }
    }

    __syncthreads();

    for (int t = 0; t < TSTEPS; ++t) {
        const unsigned short* hr = hfrag[t & 1];
        unsigned short*       hw = hfrag[(t + 1) & 1];

        const float xv = xs[t][arow];   // batch row = arow (broadcast)

        f32x4 acc[2];
#pragma unroll
        for (int mtl = 0; mtl < 2; ++mtl)
#pragma unroll
            for (int r = 0; r < 4; ++r) acc[mtl][r] = xv * wxw_c[mtl][r] + bias_c[mtl][r];

#pragma unroll
        for (int kk = 0; kk < KK; ++kk) {
            bf16x8 bf = *(const bf16x8*)(hr + (kk * 64 + lane) * 8);
            acc[0] = __builtin_amdgcn_mfma_f32_16x16x32_bf16(sa[kk & (DEPTH - 1)], bf, acc[0], 0, 0, 0);
            acc[1] = __builtin_amdgcn_mfma_f32_16x16x32_bf16(sb[kk & (DEPTH - 1)], bf, acc[1], 0, 0, 0);
            // refill slot with slice (kk+DEPTH)&15 — step-invariant stream,
            // wraps seamlessly into the next step (prefetch distance = DEPTH)
            sa[kk & (DEPTH - 1)] = wpA[((kk + DEPTH) & 15) * 64];
            sb[kk & (DEPTH - 1)] = wpB[((kk + DEPTH) & 15) * 64];
        }

        // epilogue: tanh, pack 4 consecutive out-cols -> one b64 frag-major
        // write. out-col c = wave*32 + mtl*16 + rowg*4 + r  ==> h-slice kk = wave,
        // lane = (mtl*2 + (rowg>>1))*16 + arow, j = (rowg&1)*4 + r.
#pragma unroll
        for (int mtl = 0; mtl < 2; ++mtl) {
            us4 pk;
#pragma unroll
            for (int r = 0; r < 4; ++r) {
                float v  = acc[mtl][r];
                float e  = __expf(2.0f * v);
                pk[r] = f2bf(1.0f - 2.0f / (e + 1.0f));
            }
            int chunk = mtl * 2 + (rowg >> 1);
            int j0    = (rowg & 1) * 4;
            *(us4*)(hw + (wave * 64 + chunk * 16 + arow) * 8 + j0) = pk;
        }
        lds_barrier();   // LDS ordering only — weight prefetch stays in flight
    }

    // final h is in hfrag[0] (TSTEPS even). fc head: 16 x 24 outputs.
    if (tid < BBLK * HORIZON) {
        int row = tid / HORIZON;
        int ho  = tid - row * HORIZON;
        float acc = fc_b[ho];
        const float* fw = fc_w + ho * HIDDEN;
        const unsigned short* hf = hfrag[0];
#pragma unroll 4
        for (int kk = 0; kk < KK; ++kk) {
#pragma unroll
            for (int c = 0; c < 4; ++c) {
                ushort8 hv = *(const ushort8*)(hf + (kk * 64 + c * 16 + row) * 8);
#pragma unroll
                for (int j = 0; j < 8; ++j)
                    acc += bf2f(hv[j]) * fw[kk * 32 + c * 8 + j];
            }
        }
        out[(bb + row) * HORIZON + ho] = acc;
    }
}

extern "C" void kernel_launch(void* const* d_in, const int* in_sizes, int n_in,
                              void* d_out, int out_size, void* d_ws, size_t ws_size,
                              hipStream_t stream) {
    const float* x    = (const float*)d_in[0];
    const float* Wx_w = (const float*)d_in[1];
    const float* Wx_b = (const float*)d_in[2];
    const float* Wh_w = (const float*)d_in[3];
    const float* Wh_b = (const float*)d_in[4];
    const float* fc_w = (const float*)d_in[5];
    const float* fc_b = (const float*)d_in[6];
    float* out = (float*)d_out;

    ushort8* Wpk = (ushort8*)d_ws;   // 512 KB packed weights

    hipLaunchKernelGGL(pack_wh, dim3(128), dim3(256), 0, stream, Wh_w, Wpk);
    hipLaunchKernelGGL(rnn_main, dim3(NWG), dim3(NTHR), 0, stream,
                       x, Wx_w, Wx_b, Wh_b, fc_w, fc_b,
                       (const bf16x8*)Wpk, out);
}

// Round 6
// 1104.666 us; speedup vs baseline: 1.8574x; 1.2371x over previous
//
#include <hip/hip_runtime.h>
#include <hip/hip_bf16.h>

#define HIDDEN   512
#define TSTEPS   256
#define HORIZON  24
#define BTOT     1024
#define BBLK     16
#define NWG      (BTOT / BBLK)      // 64 workgroups
#define NTHR     1024               // 16 waves
#define KK       16                 // K slices (512 / 32)

typedef __attribute__((ext_vector_type(8))) __bf16         bf16x8;
typedef __attribute__((ext_vector_type(4))) float          f32x4;
typedef __attribute__((ext_vector_type(8))) unsigned short ushort8;
typedef __attribute__((ext_vector_type(4))) unsigned short us4;
typedef __attribute__((ext_vector_type(4))) unsigned int   uint4v;

__device__ __forceinline__ unsigned short f2bf(float f) {
    unsigned int u = __float_as_uint(f);
    u += 0x7FFFu + ((u >> 16) & 1u);   // RNE
    return (unsigned short)(u >> 16);
}
__device__ __forceinline__ float bf2f(unsigned short s) {
    return __uint_as_float(((unsigned int)s) << 16);
}

// LDS-ordering-only barrier (no vmcnt drain).
__device__ __forceinline__ void lds_barrier() {
    asm volatile("s_waitcnt lgkmcnt(0)" ::: "memory");
    __builtin_amdgcn_s_barrier();
    asm volatile("" ::: "memory");
}

// Issue one weight-fragment pair (tiles A,B, same slice) via SRSRC buffer_load,
// self-incrementing the per-tile voffset inside the asm (INCSTR is a literal).
// Early-clobber dests: they are written AFTER the voffset reads.
#define LOADW(dA, dB, INCSTR)                                        \
    asm volatile("buffer_load_dwordx4 %0, %2, %4, 0 offen\n\t"       \
                 "buffer_load_dwordx4 %1, %3, %4, 0 offen\n\t"       \
                 "v_add_u32 %2, " INCSTR ", %2\n\t"                  \
                 "v_add_u32 %3, " INCSTR ", %3"                      \
                 : "=&v"(dA), "=&v"(dB), "+v"(voffA), "+v"(voffB)    \
                 : "s"(srsrc))

// Counted wait, data-tied to the two fragments about to be consumed so the
// MFMAs cannot be scheduled above it (rule #18 handled via dataflow).
#define WAITW(a, b, N) \
    asm volatile("s_waitcnt vmcnt(" #N ")" : "+v"(a), "+v"(b))

// One K-iteration: LDS h-frag read, counted wait, two MFMAs.
#define ITER(kk, N) {                                                          \
    bf16x8 bf = *(const bf16x8*)(hr + ((kk) * 64 + lane) * 8);                 \
    WAITW(sa[(kk) & 7], sb[(kk) & 7], N);                                      \
    acc0 = __builtin_amdgcn_mfma_f32_16x16x32_bf16(sa[(kk) & 7], bf, acc0, 0, 0, 0); \
    acc1 = __builtin_amdgcn_mfma_f32_16x16x32_bf16(sb[(kk) & 7], bf, acc1, 0, 0, 0); }

// Pack Wh (f32 [512][512], row j = out-col, inner k) into bf16 A-fragment
// order, m-tile-major: Wpk[(ntg*16 + kk)*64 + lane] holds 8 bf16 of
//   A[m = ntg*16 + (lane&15)][k = kk*32 + ((lane>>4)&3)*8 + j]
__global__ void pack_wh(const float* __restrict__ Wh, ushort8* __restrict__ Wpk) {
    int tid  = blockIdx.x * blockDim.x + threadIdx.x;   // 0..32767
    int lane = tid & 63;
    int kk   = (tid >> 6) & 15;
    int ntg  = tid >> 10;                                // global m-tile 0..31
    int col  = ntg * 16 + (lane & 15);                   // out-col
    int k0   = kk * 32 + ((lane >> 4) & 3) * 8;
    const float* src = Wh + col * HIDDEN + k0;
    ushort8 v;
#pragma unroll
    for (int j = 0; j < 8; ++j) v[j] = f2bf(src[j]);
    Wpk[(ntg * 16 + kk) * 64 + lane] = v;
}

__global__ __launch_bounds__(NTHR)
__attribute__((amdgpu_waves_per_eu(4, 4)))   // pin 128-VGPR tier: no spills (spills would corrupt vmcnt)
void rnn_main(
    const float* __restrict__ x,      // [1024][256]
    const float* __restrict__ Wx_w,   // [512]
    const float* __restrict__ Wx_b,   // [512]
    const float* __restrict__ Wh_b,   // [512]
    const float* __restrict__ fc_w,   // [24][512]
    const float* __restrict__ fc_b,   // [24]
    const ushort8* __restrict__ Wpk,  // packed bf16 A-fragments (512 KB)
    float* __restrict__ out)          // [1024][24]
{
    // h in B-fragment-major layout: hfrag[buf][(kk*64 + lane)*8 ushorts]
    __shared__ __align__(16) unsigned short hfrag[2][KK * 64 * 8];  // 2 x 16 KB
    __shared__ float xs[TSTEPS][BBLK];                               // 16 KB

    const int tid  = threadIdx.x;
    const int lane = tid & 63;
    const int wave = tid >> 6;       // 0..15, owns m-tiles 2w, 2w+1
    const int bb   = blockIdx.x * BBLK;
    const int arow = lane & 15;      // C/D col = batch row
    const int rowg = lane >> 4;

    // stage x transposed: xs[t][r]
    for (int i = tid; i < BBLK * TSTEPS; i += NTHR) {
        int t = i & 255, r = i >> 8;
        xs[t][r] = x[(bb + r) * TSTEPS + t];
    }
    // h0 = 0
    {
        uint4v z = {0u, 0u, 0u, 0u};
        ((uint4v*)hfrag[0])[tid] = z;
    }

    // SRSRC descriptor over the 512 KB packed-weight buffer
    uint4v srsrc;
    {
        unsigned long long b = (unsigned long long)Wpk;
        srsrc[0] = (unsigned int)b;
        srsrc[1] = (unsigned int)(b >> 32);   // stride=0
        srsrc[2] = 512 * 1024;                // num_records (bytes)
        srsrc[3] = 0x00020000;                // raw dword access
    }
    // per-tile voffset, slice 0: byte = tile*16384 + lane*16
    unsigned int voffA = ((wave * 2 + 0) * 1024 + lane) * 16;
    unsigned int voffB = ((wave * 2 + 1) * 1024 + lane) * 16;

    // per-lane step-invariant init constants: out-col = wave*32+mtl*16+rowg*4+r
    f32x4 wxw_c[2], bias_c[2];
#pragma unroll
    for (int mtl = 0; mtl < 2; ++mtl) {
#pragma unroll
        for (int r = 0; r < 4; ++r) {
            int oc = wave * 32 + mtl * 16 + rowg * 4 + r;
            wxw_c[mtl][r]  = Wx_w[oc];
            bias_c[mtl][r] = Wx_b[oc] + Wh_b[oc];
        }
    }

    __syncthreads();   // full drain: no compiler-tracked VMEM outstanding past here

    for (int t = 0; t < TSTEPS; ++t) {
        const unsigned short* hr = hfrag[t & 1];
        unsigned short*       hw = hfrag[(t + 1) & 1];

        // ---- step prologue: issue slices 0..7 (16 loads in flight) ----
        bf16x8 sa[8], sb[8];
        LOADW(sa[0], sb[0], "0x400");
        LOADW(sa[1], sb[1], "0x400");
        LOADW(sa[2], sb[2], "0x400");
        LOADW(sa[3], sb[3], "0x400");
        LOADW(sa[4], sb[4], "0x400");
        LOADW(sa[5], sb[5], "0x400");
        LOADW(sa[6], sb[6], "0x400");
        LOADW(sa[7], sb[7], "0x400");

        const float xv = xs[t][arow];   // batch row = arow (broadcast)
        f32x4 acc0, acc1;
#pragma unroll
        for (int r = 0; r < 4; ++r) {
            acc0[r] = xv * wxw_c[0][r] + bias_c[0][r];
            acc1[r] = xv * wxw_c[1][r] + bias_c[1][r];
        }

        // ---- iters 0..7: consume slice kk, issue slice kk+8 ----
        ITER(0, 14); LOADW(sa[0], sb[0], "0x400");
        ITER(1, 14); LOADW(sa[1], sb[1], "0x400");
        ITER(2, 14); LOADW(sa[2], sb[2], "0x400");
        ITER(3, 14); LOADW(sa[3], sb[3], "0x400");
        ITER(4, 14); LOADW(sa[4], sb[4], "0x400");
        ITER(5, 14); LOADW(sa[5], sb[5], "0x400");
        ITER(6, 14); LOADW(sa[6], sb[6], "0x400");
        ITER(7, 14); LOADW(sa[7], sb[7], "0xffffc400");  // wrap -15360: back to slice 0
        // ---- iters 8..15: drain ----
        ITER(8, 14);
        ITER(9, 12);
        ITER(10, 10);
        ITER(11, 8);
        ITER(12, 6);
        ITER(13, 4);
        ITER(14, 2);
        ITER(15, 0);   // step ends with vmcnt==0: compiler-tracked loads stay safe

        // epilogue: tanh, pack 4 consecutive out-cols -> one b64 frag-major
        // write. out-col = wave*32 + mtl*16 + rowg*4 + r ==> slice kk = wave,
        // lane-chunk = mtl*2 + (rowg>>1), j0 = (rowg&1)*4.
        {
            f32x4 accs[2] = {acc0, acc1};
#pragma unroll
            for (int mtl = 0; mtl < 2; ++mtl) {
                us4 pk;
#pragma unroll
                for (int r = 0; r < 4; ++r) {
                    float v = accs[mtl][r];
                    float e = __expf(2.0f * v);
                    pk[r] = f2bf(1.0f - 2.0f / (e + 1.0f));
                }
                int chunk = mtl * 2 + (rowg >> 1);
                int j0    = (rowg & 1) * 4;
                *(us4*)(hw + (wave * 64 + chunk * 16 + arow) * 8 + j0) = pk;
            }
        }
        lds_barrier();
    }

    // final h is in hfrag[0] (TSTEPS even). fc head: 16 x 24 outputs.
    if (tid < BBLK * HORIZON) {
        int row = tid / HORIZON;
        int ho  = tid - row * HORIZON;
        float acc = fc_b[ho];
        const float* fw = fc_w + ho * HIDDEN;
        const unsigned short* hf = hfrag[0];
#pragma unroll 4
        for (int kk = 0; kk < KK; ++kk) {
#pragma unroll
            for (int c = 0; c < 4; ++c) {
                ushort8 hv = *(const ushort8*)(hf + (kk * 64 + c * 16 + row) * 8);
#pragma unroll
                for (int j = 0; j < 8; ++j)
                    acc += bf2f(hv[j]) * fw[kk * 32 + c * 8 + j];
            }
        }
        out[(bb + row) * HORIZON + ho] = acc;
    }
}

extern "C" void kernel_launch(void* const* d_in, const int* in_sizes, int n_in,
                              void* d_out, int out_size, void* d_ws, size_t ws_size,
                              hipStream_t stream) {
    const float* x    = (const float*)d_in[0];
    const float* Wx_w = (const float*)d_in[1];
    const float* Wx_b = (const float*)d_in[2];
    const float* Wh_w = (const float*)d_in[3];
    const float* Wh_b = (const float*)d_in[4];
    const float* fc_w = (const float*)d_in[5];
    const float* fc_b = (const float*)d_in[6];
    float* out = (float*)d_out;

    ushort8* Wpk = (ushort8*)d_ws;   // 512 KB packed weights

    hipLaunchKernelGGL(pack_wh, dim3(128), dim3(256), 0, stream, Wh_w, Wpk);
    hipLaunchKernelGGL(rnn_main, dim3(NWG), dim3(NTHR), 0, stream,
                       x, Wx_w, Wx_b, Wh_b, fc_w, fc_b,
                       (const ushort8*)Wpk, out);
}

// Round 7
// 1005.952 us; speedup vs baseline: 2.0397x; 1.0981x over previous
//
#include <hip/hip_runtime.h>
#include <hip/hip_bf16.h>

#define HIDDEN   512
#define TSTEPS   256
#define HORIZON  24
#define BTOT     1024
#define BBLK     16
#define NWG      (BTOT / BBLK)      // 64 workgroups
#define NTHR     1024               // 16 waves
#define KK       16                 // K slices (512 / 32)

typedef __attribute__((ext_vector_type(8))) __bf16         bf16x8;
typedef __attribute__((ext_vector_type(4))) float          f32x4;
typedef __attribute__((ext_vector_type(8))) unsigned short ushort8;
typedef __attribute__((ext_vector_type(4))) unsigned short us4;
typedef __attribute__((ext_vector_type(4))) unsigned int   uint4v;

__device__ __forceinline__ unsigned short f2bf(float f) {
    unsigned int u = __float_as_uint(f);
    u += 0x7FFFu + ((u >> 16) & 1u);   // RNE
    return (unsigned short)(u >> 16);
}
__device__ __forceinline__ float bf2f(unsigned short s) {
    return __uint_as_float(((unsigned int)s) << 16);
}

// LDS-ordering-only barrier (no vmcnt drain): weight prefetch loads stay in
// flight across the step boundary.
__device__ __forceinline__ void lds_barrier() {
    asm volatile("s_waitcnt lgkmcnt(0)" ::: "memory");
    __builtin_amdgcn_s_barrier();
    asm volatile("" ::: "memory");
}

// Issue one weight-fragment pair (tiles A,B, same slice) via SRSRC buffer_load,
// self-incrementing the per-tile voffset inside the asm (INCSTR is a literal).
#define LOADW(dA, dB, INCSTR)                                        \
    asm volatile("buffer_load_dwordx4 %0, %2, %4, 0 offen\n\t"       \
                 "buffer_load_dwordx4 %1, %3, %4, 0 offen\n\t"       \
                 "v_add_u32 %2, " INCSTR ", %2\n\t"                  \
                 "v_add_u32 %3, " INCSTR ", %3"                      \
                 : "=&v"(dA), "=&v"(dB), "+v"(voffA), "+v"(voffB)    \
                 : "s"(srsrc))

// Counted wait, data-tied to the two fragments about to be consumed so the
// MFMAs cannot be scheduled above it.
#define WAITW(a, b, N) \
    asm volatile("s_waitcnt vmcnt(" #N ")" : "+v"(a), "+v"(b))

// One K-iteration: LDS h-frag read, counted wait, two MFMAs, re-issue slot.
// Steady state: 16 loads in flight at every wait, forever.
#define ITER(kk, INCSTR) {                                                     \
    bf16x8 bf = *(const bf16x8*)(hr + ((kk) * 64 + lane) * 8);                 \
    WAITW(sa[(kk) & 7], sb[(kk) & 7], 14);                                     \
    acc0 = __builtin_amdgcn_mfma_f32_16x16x32_bf16(sa[(kk) & 7], bf, acc0, 0, 0, 0); \
    acc1 = __builtin_amdgcn_mfma_f32_16x16x32_bf16(sb[(kk) & 7], bf, acc1, 0, 0, 0); \
    LOADW(sa[(kk) & 7], sb[(kk) & 7], INCSTR); }

// Pack Wh (f32 [512][512], row j = out-col, inner k) into bf16 A-fragment
// order, m-tile-major: Wpk[(ntg*16 + kk)*64 + lane] holds 8 bf16 of
//   A[m = ntg*16 + (lane&15)][k = kk*32 + ((lane>>4)&3)*8 + j]
__global__ void pack_wh(const float* __restrict__ Wh, ushort8* __restrict__ Wpk) {
    int tid  = blockIdx.x * blockDim.x + threadIdx.x;   // 0..32767
    int lane = tid & 63;
    int kk   = (tid >> 6) & 15;
    int ntg  = tid >> 10;                                // global m-tile 0..31
    int col  = ntg * 16 + (lane & 15);                   // out-col
    int k0   = kk * 32 + ((lane >> 4) & 3) * 8;
    const float* src = Wh + col * HIDDEN + k0;
    ushort8 v;
#pragma unroll
    for (int j = 0; j < 8; ++j) v[j] = f2bf(src[j]);
    Wpk[(ntg * 16 + kk) * 64 + lane] = v;
}

__global__ __launch_bounds__(NTHR)
__attribute__((amdgpu_waves_per_eu(4, 4)))   // pin 128-VGPR tier: no spills
void rnn_main(
    const float* __restrict__ x,      // [1024][256]
    const float* __restrict__ Wx_w,   // [512]
    const float* __restrict__ Wx_b,   // [512]
    const float* __restrict__ Wh_b,   // [512]
    const float* __restrict__ fc_w,   // [24][512]
    const float* __restrict__ fc_b,   // [24]
    const ushort8* __restrict__ Wpk,  // packed bf16 A-fragments (512 KB)
    float* __restrict__ out)          // [1024][24]
{
    // h in B-fragment-major layout: hfrag[buf][(kk*64 + lane)*8 ushorts]
    __shared__ __align__(16) unsigned short hfrag[2][KK * 64 * 8];  // 2 x 16 KB
    __shared__ float xs[TSTEPS][BBLK];                               // 16 KB

    const int tid  = threadIdx.x;
    const int lane = tid & 63;
    const int wave = tid >> 6;       // 0..15, owns m-tiles 2w, 2w+1
    const int bb   = blockIdx.x * BBLK;
    const int arow = lane & 15;      // C/D col = batch row
    const int rowg = lane >> 4;

    // stage x transposed: xs[t][r]
    for (int i = tid; i < BBLK * TSTEPS; i += NTHR) {
        int t = i & 255, r = i >> 8;
        xs[t][r] = x[(bb + r) * TSTEPS + t];
    }
    // h0 = 0
    {
        uint4v z = {0u, 0u, 0u, 0u};
        ((uint4v*)hfrag[0])[tid] = z;
    }

    // SRSRC descriptor over the 512 KB packed-weight buffer
    uint4v srsrc;
    {
        unsigned long long b = (unsigned long long)Wpk;
        srsrc[0] = (unsigned int)b;
        srsrc[1] = (unsigned int)(b >> 32);   // stride=0
        srsrc[2] = 512 * 1024;                // num_records (bytes)
        srsrc[3] = 0x00020000;                // raw dword access
    }
    // per-tile voffset, slice 0: byte = tile*16384 + lane*16
    unsigned int voffA = ((wave * 2 + 0) * 1024 + lane) * 16;
    unsigned int voffB = ((wave * 2 + 1) * 1024 + lane) * 16;

    // per-lane step-invariant init constants: out-col = wave*32+mtl*16+rowg*4+r
    f32x4 wxw_c[2], bias_c[2];
#pragma unroll
    for (int mtl = 0; mtl < 2; ++mtl) {
#pragma unroll
        for (int r = 0; r < 4; ++r) {
            int oc = wave * 32 + mtl * 16 + rowg * 4 + r;
            wxw_c[mtl][r]  = Wx_w[oc];
            bias_c[mtl][r] = Wx_b[oc] + Wh_b[oc];
        }
    }

    __syncthreads();   // full drain: no compiler-tracked VMEM outstanding past here

    // ---- persistent prologue: issue slices 0..7 once (16 loads in flight,
    //      and the pipeline NEVER drains until after the t-loop) ----
    bf16x8 sa[8], sb[8];
    LOADW(sa[0], sb[0], "0x400");
    LOADW(sa[1], sb[1], "0x400");
    LOADW(sa[2], sb[2], "0x400");
    LOADW(sa[3], sb[3], "0x400");
    LOADW(sa[4], sb[4], "0x400");
    LOADW(sa[5], sb[5], "0x400");
    LOADW(sa[6], sb[6], "0x400");
    LOADW(sa[7], sb[7], "0x400");   // voff now at slice 8

#pragma clang loop unroll(disable)
    for (int t = 0; t < TSTEPS; ++t) {
        const unsigned short* hr = hfrag[t & 1];
        unsigned short*       hw = hfrag[(t + 1) & 1];

        const float xv = xs[t][arow];   // batch row = arow (broadcast)
        f32x4 acc0, acc1;
#pragma unroll
        for (int r = 0; r < 4; ++r) {
            acc0[r] = xv * wxw_c[0][r] + bias_c[0][r];
            acc1[r] = xv * wxw_c[1][r] + bias_c[1][r];
        }

        // iters 0..7 re-issue slices 8..15 (this step); iter 7 wraps voff.
        // iters 8..15 re-issue slices 0..7 (NEXT step) — they mature across
        // the epilogue + barrier, killing the per-step cold bubble.
        ITER(0,  "0x400");
        ITER(1,  "0x400");
        ITER(2,  "0x400");
        ITER(3,  "0x400");
        ITER(4,  "0x400");
        ITER(5,  "0x400");
        ITER(6,  "0x400");
        ITER(7,  "0xffffc400");   // wrap: -15360 -> back to slice 0
        ITER(8,  "0x400");
        ITER(9,  "0x400");
        ITER(10, "0x400");
        ITER(11, "0x400");
        ITER(12, "0x400");
        ITER(13, "0x400");
        ITER(14, "0x400");
        ITER(15, "0x400");        // voff back at slice 8 for next step

        // epilogue: tanh, pack 4 consecutive out-cols -> one b64 frag-major
        // write. out-col = wave*32 + mtl*16 + rowg*4 + r ==> slice kk = wave,
        // lane-chunk = mtl*2 + (rowg>>1), j0 = (rowg&1)*4.
        {
            f32x4 accs[2] = {acc0, acc1};
#pragma unroll
            for (int mtl = 0; mtl < 2; ++mtl) {
                us4 pk;
#pragma unroll
                for (int r = 0; r < 4; ++r) {
                    float v = accs[mtl][r];
                    float e = __expf(2.0f * v);
                    pk[r] = f2bf(1.0f - 2.0f / (e + 1.0f));
                }
                int chunk = mtl * 2 + (rowg >> 1);
                int j0    = (rowg & 1) * 4;
                *(us4*)(hw + (wave * 64 + chunk * 16 + arow) * 8 + j0) = pk;
            }
        }
        lds_barrier();
    }

    // Drain the persistent stream. Slots are asm inputs so their registers
    // stay live until all in-flight loads have landed (no early reuse).
    asm volatile("s_waitcnt vmcnt(0)"
                 :: "v"(sa[0]), "v"(sa[1]), "v"(sa[2]), "v"(sa[3]),
                    "v"(sa[4]), "v"(sa[5]), "v"(sa[6]), "v"(sa[7]),
                    "v"(sb[0]), "v"(sb[1]), "v"(sb[2]), "v"(sb[3]),
                    "v"(sb[4]), "v"(sb[5]), "v"(sb[6]), "v"(sb[7])
                 : "memory");

    // final h is in hfrag[0] (TSTEPS even). fc head: 16 x 24 outputs.
    if (tid < BBLK * HORIZON) {
        int row = tid / HORIZON;
        int ho  = tid - row * HORIZON;
        float acc = fc_b[ho];
        const float* fw = fc_w + ho * HIDDEN;
        const unsigned short* hf = hfrag[0];
#pragma unroll 4
        for (int kk = 0; kk < KK; ++kk) {
#pragma unroll
            for (int c = 0; c < 4; ++c) {
                ushort8 hv = *(const ushort8*)(hf + (kk * 64 + c * 16 + row) * 8);
#pragma unroll
                for (int j = 0; j < 8; ++j)
                    acc += bf2f(hv[j]) * fw[kk * 32 + c * 8 + j];
            }
        }
        out[(bb + row) * HORIZON + ho] = acc;
    }
}

extern "C" void kernel_launch(void* const* d_in, const int* in_sizes, int n_in,
                              void* d_out, int out_size, void* d_ws, size_t ws_size,
                              hipStream_t stream) {
    const float* x    = (const float*)d_in[0];
    const float* Wx_w = (const float*)d_in[1];
    const float* Wx_b = (const float*)d_in[2];
    const float* Wh_w = (const float*)d_in[3];
    const float* Wh_b = (const float*)d_in[4];
    const float* fc_w = (const float*)d_in[5];
    const float* fc_b = (const float*)d_in[6];
    float* out = (float*)d_out;

    ushort8* Wpk = (ushort8*)d_ws;   // 512 KB packed weights

    hipLaunchKernelGGL(pack_wh, dim3(128), dim3(256), 0, stream, Wh_w, Wpk);
    hipLaunchKernelGGL(rnn_main, dim3(NWG), dim3(NTHR), 0, stream,
                       x, Wx_w, Wx_b, Wh_b, fc_w, fc_b,
                       (const ushort8*)Wpk, out);
}